// Round 20
// baseline (454.954 us; speedup 1.0000x reference)
//
#include <hip/hip_runtime.h>
#include <hip/hip_cooperative_groups.h>
#include <math.h>

namespace cg = cooperative_groups;

#define NHEADS 4
#define HDIM 32
#define F 128    // Fin == H*C == 128 for both layers
#define ACH 8192 // edges per block in bucket pass A (512-thread blocks, 16 iters)
#define LOG2E 1.44269504088896340736f

typedef __attribute__((ext_vector_type(8))) short bf16x8;
typedef __attribute__((ext_vector_type(4))) float f32x4;
typedef __attribute__((ext_vector_type(4))) unsigned u32x4;

__device__ __forceinline__ float lrelu(float v) { return v > 0.f ? v : 0.2f * v; }

__device__ __forceinline__ unsigned short cvt_bf16(float f) {
    unsigned u = __float_as_uint(f);
    u += 0x7fffu + ((u >> 16) & 1u);     // round-to-nearest-even
    return (unsigned short)(u >> 16);
}

// ---------------- MFMA GEMM: h = x @ W, fused alpha, bf16 h out ---------------
// alpha outputs are scaled by log2(e) so the aggregate can use exp2 directly.
template<bool ABF16>
__global__ __launch_bounds__(256) void k_gemm_mfma(
    const void* __restrict__ xv, const short* __restrict__ Wb,
    unsigned short* __restrict__ hbf, float* __restrict__ as_out,
    float* __restrict__ ad_out, int N)
{
    const int wid  = threadIdx.x >> 6;
    const int lane = threadIdx.x & 63;
    const int rowbase = blockIdx.x * 64 + wid * 16;
    const int row  = rowbase + (lane & 15);
    const int rowc = min(row, N - 1);
    const int col = lane & 15;

    f32x4 acc[9] = {};
    #pragma unroll
    for (int kk = 0; kk < 4; ++kk) {
        bf16x8 a;
        if constexpr (ABF16) {
            const unsigned short* xr =
                (const unsigned short*)xv + (size_t)rowc * F + (lane >> 4) * 8;
            a = *(const bf16x8*)(xr + kk * 32);
        } else {
            const float* xr = (const float*)xv + (size_t)rowc * F + (lane >> 4) * 8;
            float4 xa = *(const float4*)(xr + kk * 32);
            float4 xb = *(const float4*)(xr + kk * 32 + 4);
            a[0] = cvt_bf16(xa.x); a[1] = cvt_bf16(xa.y);
            a[2] = cvt_bf16(xa.z); a[3] = cvt_bf16(xa.w);
            a[4] = cvt_bf16(xb.x); a[5] = cvt_bf16(xb.y);
            a[6] = cvt_bf16(xb.z); a[7] = cvt_bf16(xb.w);
        }
        const bf16x8* bp = (const bf16x8*)(Wb + (size_t)(kk * 9) * 512 + lane * 8);
        #pragma unroll
        for (int ct = 0; ct < 9; ++ct) {
            bf16x8 b = bp[ct * 64];
            acc[ct] = __builtin_amdgcn_mfma_f32_16x16x32_bf16(a, b, acc[ct], 0, 0, 0);
        }
    }

    const int r0 = rowbase + (lane >> 4) * 4;
    #pragma unroll
    for (int i = 0; i < 4; ++i) {
        int r = r0 + i;
        if (r < N) {
            #pragma unroll
            for (int ct = 0; ct < 8; ++ct)
                __builtin_nontemporal_store(cvt_bf16(acc[ct][i]),
                                            &hbf[(size_t)r * F + ct * 16 + col]);
            if (col < 4)       as_out[r * NHEADS + col]     = acc[8][i] * LOG2E;
            else if (col < 8)  ad_out[r * NHEADS + col - 4] = acc[8][i] * LOG2E;
        }
    }
}

// ============ Cooperative preprocessing: pack + CSR build + degree sort =======
// One kernel, grid = nab blocks x 512 threads (all-resident), phases separated
// by grid.sync(). bucket = dst>>8; edge packed as (src<<8)|(dst&255).
struct PrepArgs {
    const int* src; const int* dst;
    const float *W1, *as1, *ad1, *W2, *as2, *ad2;
    short* Wb;
    int* bha; int* bbase; int* bh;
    unsigned* epack; int* deg; int* rowptr; int* ssrc;
    int4* ninfo;
    int N, E, TOT, nbuc, nab, nb;
};

__global__ __launch_bounds__(512) void k_prep(PrepArgs a)
{
    cg::grid_group grid = cg::this_grid();
    __shared__ int lds0[512];
    __shared__ int lhist[256];
    __shared__ int lsh[256];
    __shared__ int lcur[256];
    const int t = threadIdx.x;
    const int b = blockIdx.x;
    const int nbuc = a.nbuc, nab = a.nab, nb = a.nb, N = a.N, E = a.E, TOT = a.TOT;

    // ---- phase 0: per-chunk bucket histogram + W pre-pack (grid-stride) ----
    lds0[t] = 0;
    __syncthreads();
    {
        int base = b * ACH;
        for (int k = 0; k < ACH / 512; ++k) {
            int i = base + k * 512 + t;
            if (i < TOT) {
                int d = (i < E) ? a.dst[i] : (i - E);
                atomicAdd(&lds0[d >> 8], 1);
            }
        }
    }
    for (int idx = b * 512 + t; idx < 2 * 36 * 512; idx += (int)gridDim.x * 512) {
        int half = idx >= 36 * 512;
        const float* W     = half ? a.W2 : a.W1;
        const float* a_src = half ? a.as2 : a.as1;
        const float* a_dst = half ? a.ad2 : a.ad1;
        int r = idx - half * 36 * 512;
        int j    = r & 7;
        int lane = (r >> 3) & 63;
        int frag = r >> 9;
        int kk = frag / 9, ct = frag % 9;
        int k = kk * 32 + (lane >> 4) * 8 + j;
        int col = lane & 15;
        float val;
        if (ct < 8) {
            val = W[k * F + ct * 16 + col];
        } else if (col < 8) {
            int head = col & 3;
            const float* av = (col < 4) ? a_src : a_dst;
            float sum = 0.f;
            #pragma unroll 8
            for (int c = 0; c < HDIM; ++c)
                sum += W[k * F + head * HDIM + c] * av[head * HDIM + c];
            val = sum;
        } else {
            val = 0.f;
        }
        a.Wb[idx] = (short)cvt_bf16(val);
    }
    __syncthreads();
    if (t < nbuc) a.bha[(size_t)b * nbuc + t] = lds0[t];
    __threadfence();
    grid.sync();

    // ---- phase 1 (block 0): column scan + bucket-base scan + zero bh ----
    if (b == 0) {
        for (int i = t; i < nb * 256; i += 512) a.bh[i] = 0;
        int run = 0;
        if (t < nbuc) {
            int j = 0;
            for (; j + 8 <= nab; j += 8) {
                int v[8];
                #pragma unroll
                for (int u = 0; u < 8; ++u) v[u] = a.bha[(size_t)(j + u) * nbuc + t];
                #pragma unroll
                for (int u = 0; u < 8; ++u) { a.bha[(size_t)(j + u) * nbuc + t] = run; run += v[u]; }
            }
            for (; j < nab; ++j) {
                int v = a.bha[(size_t)j * nbuc + t];
                a.bha[(size_t)j * nbuc + t] = run; run += v;
            }
        }
        lds0[t] = run;
        __syncthreads();
        for (int off = 1; off < 512; off <<= 1) {
            int u = (t >= off) ? lds0[t - off] : 0;
            __syncthreads();
            lds0[t] += u;
            __syncthreads();
        }
        if (t < nbuc) {
            a.bbase[t] = lds0[t] - run;
            if (t == nbuc - 1) a.bbase[nbuc] = lds0[t];
        }
    }
    __threadfence();
    grid.sync();

    // ---- phase 2: scatter packed edges (block-private bucket regions) ----
    lds0[t] = (t < nbuc) ? (a.bha[(size_t)b * nbuc + t] + a.bbase[t]) : 0;
    __syncthreads();
    {
        int base = b * ACH;
        for (int k = 0; k < ACH / 512; ++k) {
            int i = base + k * 512 + t;
            if (i < TOT) {
                int s, d;
                if (i < E) { s = a.src[i]; d = a.dst[i]; } else { s = d = i - E; }
                int pos = atomicAdd(&lds0[d >> 8], 1);
                a.epack[pos] = ((unsigned)s << 8) | (unsigned)(d & 255);
            }
        }
    }
    __threadfence();
    grid.sync();

    // ---- phase 3: per-bucket deg + rowptr + CSR scatter + sort histogram ----
    for (int bk = b; bk < nbuc; bk += (int)gridDim.x) {
        if (t < 256) lhist[t] = 0;
        __syncthreads();
        int s0 = a.bbase[bk], s1 = a.bbase[bk + 1];
        for (int i = s0 + t; i < s1; i += 512)
            atomicAdd(&lhist[a.epack[i] & 255u], 1);
        __syncthreads();
        int h = 0;
        if (t < 256) { h = lhist[t]; lsh[t] = h; }
        __syncthreads();
        for (int off = 1; off < 256; off <<= 1) {
            int u = (t >= off && t < 256) ? lsh[t - off] : 0;
            __syncthreads();
            if (t < 256) lsh[t] += u;
            __syncthreads();
        }
        if (t < 256) {
            int node = bk * 256 + t;
            int excl = s0 + lsh[t] - h;
            lcur[t] = excl;
            if (node < N) {
                a.deg[node] = h;
                a.rowptr[node] = excl;
                atomicAdd(&a.bh[(bk >> 2) * 256 + min(h, 255)], 1);
            }
            if (node == 0) a.rowptr[N] = a.bbase[nbuc];
        }
        __syncthreads();
        for (int i = s0 + t; i < s1; i += 512) {
            unsigned p = a.epack[i];
            int pos = atomicAdd(&lcur[p & 255u], 1);
            a.ssrc[pos] = (int)(p >> 8);
        }
        __syncthreads();
    }
    __threadfence();
    grid.sync();

    // ---- phase 4 (block 0): degree-sort offsets, DESCENDING degree ----
    if (b == 0) {
        int run = 0;
        if (t < 256) {
            int j = 0;
            for (; j + 8 <= nb; j += 8) {
                int v[8];
                #pragma unroll
                for (int u = 0; u < 8; ++u) v[u] = a.bh[(j + u) * 256 + t];
                #pragma unroll
                for (int u = 0; u < 8; ++u) { a.bh[(j + u) * 256 + t] = run; run += v[u]; }
            }
            for (; j < nb; ++j) {
                int v = a.bh[j * 256 + t];
                a.bh[j * 256 + t] = run;
                run += v;
            }
            lsh[t] = run;
        }
        __syncthreads();
        for (int off = 1; off < 256; off <<= 1) {
            int u = (t >= off && t < 256) ? lsh[t - off] : 0;
            __syncthreads();
            if (t < 256) lsh[t] += u;
            __syncthreads();
        }
        int total = lsh[255];
        if (t < 256) {
            int bucket_base = total - lsh[t];   // descending: buckets > t first
            for (int j2 = 0; j2 < nb; ++j2)
                a.bh[j2 * 256 + t] += bucket_base;
        }
    }
    __threadfence();
    grid.sync();

    // ---- phase 5: sort scatter -> ninfo {start, end, node} ----
    for (int cb = b; cb < nb; cb += (int)gridDim.x) {
        if (t < 256) lcur[t] = a.bh[cb * 256 + t];
        __syncthreads();
        int base = cb * 1024;
        #pragma unroll
        for (int g = 0; g < 2; ++g) {
            int i = base + g * 512 + t;
            if (i < N) {
                int pos = atomicAdd(&lcur[min(a.deg[i], 255)], 1);
                a.ninfo[pos] = make_int4(a.rowptr[i], a.rowptr[i + 1], i, 0);
            }
        }
        __syncthreads();
    }
}

// ---------------- single-pass softmax + weighted aggregation ----------------
// 16 lanes per node (descending-degree order), 4 nodes per wave. 8 edges
// batched per iteration; tail edges index-clamped+predicated. Logits are
// pre-scaled by log2(e) so exp2f (bare v_exp_f32) is exact softmax math.
template<bool OUTBF16>
__global__ __launch_bounds__(256) void k_aggregate(
    const int4* __restrict__ ninfo, const int* __restrict__ ssrc,
    const float* __restrict__ as, const float* __restrict__ ad,
    const unsigned short* __restrict__ hbf, const float* __restrict__ bias,
    void* __restrict__ outv, int N)
{
    int gi = (blockIdx.x * 256 + threadIdx.x) >> 4;
    if (gi >= N) return;
    const int4 ni   = ninfo[gi];           // broadcast within the 16-lane group
    const int start = ni.x, end = ni.y, node = ni.z;
    const int l16   = threadIdx.x & 15;
    const int hb    = l16 >> 2;
    const int c0    = l16 * 8;
    const float adB = ad[node * NHEADS + hb];

    float a0=0.f,a1=0.f,a2=0.f,a3=0.f,a4=0.f,a5=0.f,a6=0.f,a7=0.f;
    float dacc = 0.f;
    for (int base = start; base < end; base += 8) {
        int   sj[8];
        float fj[8];
        uint4 hj[8];
        #pragma unroll
        for (int j = 0; j < 8; ++j)
            sj[j] = ssrc[min(base + j, end - 1)];
        #pragma unroll
        for (int j = 0; j < 8; ++j)
            fj[j] = as[sj[j] * NHEADS + hb];
        #pragma unroll
        for (int j = 0; j < 8; ++j)
            hj[j] = *(const uint4*)(hbf + (size_t)sj[j] * F + c0);
        #pragma unroll
        for (int j = 0; j < 8; ++j) {
            float ex = (base + j < end) ? exp2f(lrelu(fj[j] + adB)) : 0.f;
            dacc += ex;
            a0 = fmaf(ex, __uint_as_float(hj[j].x << 16),         a0);
            a1 = fmaf(ex, __uint_as_float(hj[j].x & 0xffff0000u), a1);
            a2 = fmaf(ex, __uint_as_float(hj[j].y << 16),         a2);
            a3 = fmaf(ex, __uint_as_float(hj[j].y & 0xffff0000u), a3);
            a4 = fmaf(ex, __uint_as_float(hj[j].z << 16),         a4);
            a5 = fmaf(ex, __uint_as_float(hj[j].z & 0xffff0000u), a5);
            a6 = fmaf(ex, __uint_as_float(hj[j].w << 16),         a6);
            a7 = fmaf(ex, __uint_as_float(hj[j].w & 0xffff0000u), a7);
        }
    }
    float inv = 1.f / dacc;
    float v[8] = {a0,a1,a2,a3,a4,a5,a6,a7};
    #pragma unroll
    for (int k = 0; k < 8; ++k) {
        float t = v[k] * inv + bias[c0 + k];
        v[k] = t > 0.f ? t : expm1f(t);
    }
    if (OUTBF16) {
        u32x4 o;
        o.x = (unsigned)cvt_bf16(v[0]) | ((unsigned)cvt_bf16(v[1]) << 16);
        o.y = (unsigned)cvt_bf16(v[2]) | ((unsigned)cvt_bf16(v[3]) << 16);
        o.z = (unsigned)cvt_bf16(v[4]) | ((unsigned)cvt_bf16(v[5]) << 16);
        o.w = (unsigned)cvt_bf16(v[6]) | ((unsigned)cvt_bf16(v[7]) << 16);
        __builtin_nontemporal_store(o,
            (u32x4*)((unsigned short*)outv + (size_t)node * F + c0));
    } else {
        f32x4 o0 = {v[0], v[1], v[2], v[3]};
        f32x4 o1 = {v[4], v[5], v[6], v[7]};
        float* op = (float*)outv + (size_t)node * F + c0;
        __builtin_nontemporal_store(o0, (f32x4*)op);
        __builtin_nontemporal_store(o1, (f32x4*)(op + 4));
    }
}

extern "C" void kernel_launch(void* const* d_in, const int* in_sizes, int n_in,
                              void* d_out, int out_size, void* d_ws, size_t ws_size,
                              hipStream_t stream)
{
    const float* x      = (const float*)d_in[0];
    const int*   eidx   = (const int*)d_in[1];
    const float* W1     = (const float*)d_in[2];
    const float* a_src1 = (const float*)d_in[3];
    const float* a_dst1 = (const float*)d_in[4];
    const float* b1     = (const float*)d_in[5];
    const float* W2     = (const float*)d_in[6];
    const float* a_src2 = (const float*)d_in[7];
    const float* a_dst2 = (const float*)d_in[8];
    const float* b2     = (const float*)d_in[9];

    const int N = in_sizes[0] / F;
    const int E = in_sizes[1] / 2;
    const int TOT = E + N;
    const int* src = eidx;
    const int* dst = eidx + E;

    const int nbuc = (N + 255) / 256;        // coarse buckets (dst>>8)
    const int nab  = (TOT + ACH - 1) / ACH;  // pass-A blocks (all-resident coop grid)
    const int nb   = (N + 1023) / 1024;      // degree-sort blocks

    // workspace layout
    unsigned* epack = (unsigned*)d_ws;                     // TOT
    unsigned short* hbf    = (unsigned short*)(epack + TOT);   // N*F bf16
    unsigned short* out1bf = hbf + (size_t)N * F;          // N*F bf16
    float* as = (float*)(out1bf + (size_t)N * F);          // N*4
    float* ad = as + (size_t)N * NHEADS;                   // N*4
    int* deg    = (int*)(ad + (size_t)N * NHEADS);         // N
    int* rowptr = deg + N;                                 // N+1
    int* ssrc   = rowptr + N + 1;                          // TOT
    int4* ninfo = (int4*)(((uintptr_t)(ssrc + TOT) + 15) & ~(uintptr_t)15); // N
    int* bh     = (int*)(ninfo + N);                       // nb*256
    int* bha    = bh + (size_t)nb * 256;                   // nab*nbuc
    int* btot   = bha + (size_t)nab * nbuc;                // nbuc (layout keep)
    int* bbase  = btot + nbuc;                             // nbuc+1
    short* Wb1  = (short*)(((uintptr_t)(bbase + nbuc + 1) + 15) & ~(uintptr_t)15);
    short* Wb2  = Wb1 + 36 * 512;

    const int gemmBlocks = (N + 63) / 64;
    const int aggBlocks  = (N + 15) / 16;

    // ---- cooperative preprocessing (pack + CSR + sort) ----
    PrepArgs pa;
    pa.src = src; pa.dst = dst;
    pa.W1 = W1; pa.as1 = a_src1; pa.ad1 = a_dst1;
    pa.W2 = W2; pa.as2 = a_src2; pa.ad2 = a_dst2;
    pa.Wb = Wb1;
    pa.bha = bha; pa.bbase = bbase; pa.bh = bh;
    pa.epack = epack; pa.deg = deg; pa.rowptr = rowptr; pa.ssrc = ssrc;
    pa.ninfo = ninfo;
    pa.N = N; pa.E = E; pa.TOT = TOT; pa.nbuc = nbuc; pa.nab = nab; pa.nb = nb;
    void* kargs[] = { &pa };
    (void)hipLaunchCooperativeKernel((void*)k_prep, dim3(nab), dim3(512),
                                     kargs, 0, stream);

    // ---- layer 1: x (f32) -> out1bf (bf16) ----
    k_gemm_mfma<false><<<gemmBlocks, 256, 0, stream>>>(x, Wb1, hbf, as, ad, N);
    k_aggregate<true><<<aggBlocks, 256, 0, stream>>>(ninfo, ssrc, as, ad, hbf, b1, out1bf, N);

    // ---- layer 2: out1bf (bf16) -> d_out (f32) ----
    k_gemm_mfma<true><<<gemmBlocks, 256, 0, stream>>>(out1bf, Wb2, hbf, as, ad, N);
    k_aggregate<false><<<aggBlocks, 256, 0, stream>>>(ninfo, ssrc, as, ad, hbf, b2, d_out, N);
}

// Round 21
// 240.374 us; speedup vs baseline: 1.8927x; 1.8927x over previous
//
#include <hip/hip_runtime.h>
#include <math.h>

#define NHEADS 4
#define HDIM 32
#define F 128    // Fin == H*C == 128 for both layers
#define ACH 8192 // edges per block in bucket pass A (512-thread blocks, 16 iters)
#define LOG2E 1.44269504088896340736f

typedef __attribute__((ext_vector_type(8))) short bf16x8;
typedef __attribute__((ext_vector_type(4))) float f32x4;
typedef __attribute__((ext_vector_type(4))) unsigned u32x4;

__device__ __forceinline__ float lrelu(float v) { return v > 0.f ? v : 0.2f * v; }

__device__ __forceinline__ unsigned short cvt_bf16(float f) {
    unsigned u = __float_as_uint(f);
    u += 0x7fffu + ((u >> 16) & 1u);     // round-to-nearest-even
    return (unsigned short)(u >> 16);
}

// ---------------- W pre-pack, both layers in one launch ----------------
// ct==8 is the fused-alpha fragment: cols 0-3 = (W @ a_src)[k][head],
// cols 4-7 = (W @ a_dst)[k][head-4], cols 8-15 = 0.
__global__ void k_packW2(const float* __restrict__ W1, const float* __restrict__ as1,
                         const float* __restrict__ ad1, const float* __restrict__ W2,
                         const float* __restrict__ as2, const float* __restrict__ ad2,
                         short* __restrict__ Wb) {
    int idx = blockIdx.x * 256 + threadIdx.x;
    if (idx >= 2 * 36 * 512) return;
    int half = idx >= 36 * 512;
    const float* W     = half ? W2 : W1;
    const float* a_src = half ? as2 : as1;
    const float* a_dst = half ? ad2 : ad1;
    int r = idx - half * 36 * 512;
    int j    = r & 7;
    int lane = (r >> 3) & 63;
    int frag = r >> 9;
    int kk = frag / 9, ct = frag % 9;
    int k = kk * 32 + (lane >> 4) * 8 + j;
    int col = lane & 15;
    float val;
    if (ct < 8) {
        val = W[k * F + ct * 16 + col];
    } else if (col < 8) {
        int head = col & 3;
        const float* av = (col < 4) ? a_src : a_dst;
        float sum = 0.f;
        #pragma unroll 8
        for (int c = 0; c < HDIM; ++c)
            sum += W[k * F + head * HDIM + c] * av[head * HDIM + c];
        val = sum;
    } else {
        val = 0.f;
    }
    Wb[idx] = (short)cvt_bf16(val);
}

// ---------------- MFMA GEMM: h = x @ W, fused alpha, bf16 h out ---------------
// alpha outputs are scaled by log2(e) so the aggregate can use exp2 directly.
template<bool ABF16>
__global__ __launch_bounds__(256) void k_gemm_mfma(
    const void* __restrict__ xv, const short* __restrict__ Wb,
    unsigned short* __restrict__ hbf, float* __restrict__ as_out,
    float* __restrict__ ad_out, int N)
{
    const int wid  = threadIdx.x >> 6;
    const int lane = threadIdx.x & 63;
    const int rowbase = blockIdx.x * 64 + wid * 16;
    const int row  = rowbase + (lane & 15);
    const int rowc = min(row, N - 1);
    const int col = lane & 15;

    f32x4 acc[9] = {};
    #pragma unroll
    for (int kk = 0; kk < 4; ++kk) {
        bf16x8 a;
        if constexpr (ABF16) {
            const unsigned short* xr =
                (const unsigned short*)xv + (size_t)rowc * F + (lane >> 4) * 8;
            a = *(const bf16x8*)(xr + kk * 32);
        } else {
            const float* xr = (const float*)xv + (size_t)rowc * F + (lane >> 4) * 8;
            float4 xa = *(const float4*)(xr + kk * 32);
            float4 xb = *(const float4*)(xr + kk * 32 + 4);
            a[0] = cvt_bf16(xa.x); a[1] = cvt_bf16(xa.y);
            a[2] = cvt_bf16(xa.z); a[3] = cvt_bf16(xa.w);
            a[4] = cvt_bf16(xb.x); a[5] = cvt_bf16(xb.y);
            a[6] = cvt_bf16(xb.z); a[7] = cvt_bf16(xb.w);
        }
        const bf16x8* bp = (const bf16x8*)(Wb + (size_t)(kk * 9) * 512 + lane * 8);
        #pragma unroll
        for (int ct = 0; ct < 9; ++ct) {
            bf16x8 b = bp[ct * 64];
            acc[ct] = __builtin_amdgcn_mfma_f32_16x16x32_bf16(a, b, acc[ct], 0, 0, 0);
        }
    }

    const int r0 = rowbase + (lane >> 4) * 4;
    #pragma unroll
    for (int i = 0; i < 4; ++i) {
        int r = r0 + i;
        if (r < N) {
            #pragma unroll
            for (int ct = 0; ct < 8; ++ct)
                __builtin_nontemporal_store(cvt_bf16(acc[ct][i]),
                                            &hbf[(size_t)r * F + ct * 16 + col]);
            if (col < 4)       as_out[r * NHEADS + col]     = acc[8][i] * LOG2E;
            else if (col < 8)  ad_out[r * NHEADS + col - 4] = acc[8][i] * LOG2E;
        }
    }
}

// ============ CSR build via coarse buckets (no global atomics) ============
// bucket = dst >> 8 (256 nodes each). Edge record packed into one uint:
// (src << 8) | (dst & 255) -- bucket id is implicit in position.

// A1: per-block histogram over nbuc buckets (512 threads, 16 iters/block)
__global__ __launch_bounds__(512) void k_bhist(
    const int* __restrict__ src, const int* __restrict__ dst,
    int* __restrict__ bha, int nbuc, int E, int TOT)
{
    __shared__ int hist[512];
    int t = threadIdx.x;
    hist[t] = 0;
    __syncthreads();
    int base = blockIdx.x * ACH;
    for (int k = 0; k < ACH / 512; ++k) {
        int i = base + k * 512 + t;
        if (i < TOT) {
            int d = (i < E) ? dst[i] : (i - E);
            atomicAdd(&hist[d >> 8], 1);
        }
    }
    __syncthreads();
    if (t < nbuc) bha[(size_t)blockIdx.x * nbuc + t] = hist[t];
}

// Merged scan: per-bucket column prefix over nab A-blocks (8-deep MLP),
// then bucket-base exclusive scan, in one single-block kernel.
// Also zeroes the degree-sort histogram bh (nbh ints) for later use.
__global__ __launch_bounds__(512) void k_bscan(
    int* __restrict__ bha, int* __restrict__ bbase, int* __restrict__ bh,
    int nbuc, int nab, int nbh)
{
    int t = threadIdx.x;
    for (int i = t; i < nbh; i += 512) bh[i] = 0;
    int run = 0;
    if (t < nbuc) {
        int j = 0;
        for (; j + 8 <= nab; j += 8) {
            int v[8];
            #pragma unroll
            for (int u = 0; u < 8; ++u) v[u] = bha[(size_t)(j + u) * nbuc + t];
            #pragma unroll
            for (int u = 0; u < 8; ++u) { bha[(size_t)(j + u) * nbuc + t] = run; run += v[u]; }
        }
        for (; j < nab; ++j) {
            int v = bha[(size_t)j * nbuc + t];
            bha[(size_t)j * nbuc + t] = run; run += v;
        }
    }
    __shared__ int sh[512];
    sh[t] = run;
    __syncthreads();
    for (int off = 1; off < 512; off <<= 1) {
        int u = (t >= off) ? sh[t - off] : 0;
        __syncthreads();
        sh[t] += u;
        __syncthreads();
    }
    if (t < nbuc) {
        bbase[t] = sh[t] - run;
        if (t == nbuc - 1) bbase[nbuc] = sh[t];
    }
}

// A2: scatter packed edges into bucket-major array; cursor = per-block
// intra-bucket offset + bucket base.
__global__ __launch_bounds__(512) void k_bscatter(
    const int* __restrict__ src, const int* __restrict__ dst,
    const int* __restrict__ bha, const int* __restrict__ bbase,
    unsigned* __restrict__ epack, int nbuc, int E, int TOT)
{
    __shared__ int cur[512];
    int t = threadIdx.x;
    cur[t] = (t < nbuc) ? (bha[(size_t)blockIdx.x * nbuc + t] + bbase[t]) : 0;
    __syncthreads();
    int base = blockIdx.x * ACH;
    for (int k = 0; k < ACH / 512; ++k) {
        int i = base + k * 512 + t;
        if (i < TOT) {
            int s, d;
            if (i < E) { s = src[i]; d = dst[i]; } else { s = d = i - E; }
            int pos = atomicAdd(&cur[d >> 8], 1);
            epack[pos] = ((unsigned)s << 8) | (unsigned)(d & 255);
        }
    }
}

// B (fused): per-bucket deg + rowptr + final CSR scatter + degree-sort
// histogram contribution (bh zeroed by k_bscan; fire-and-forget atomics).
__global__ __launch_bounds__(256) void k_bfinal(
    const unsigned* __restrict__ epack, const int* __restrict__ bbase,
    int* __restrict__ deg, int* __restrict__ rowptr, int* __restrict__ ssrc,
    int* __restrict__ bh, int N, int nbuc)
{
    __shared__ int hist[256];
    __shared__ int sh[256];
    __shared__ int cur[256];
    int t = threadIdx.x;
    hist[t] = 0;
    __syncthreads();
    int s0 = bbase[blockIdx.x], s1 = bbase[blockIdx.x + 1];
    for (int i = s0 + t; i < s1; i += 256)
        atomicAdd(&hist[epack[i] & 255u], 1);
    __syncthreads();
    int h = hist[t];
    sh[t] = h;
    __syncthreads();
    for (int off = 1; off < 256; off <<= 1) {
        int u = (t >= off) ? sh[t - off] : 0;
        __syncthreads();
        sh[t] += u;
        __syncthreads();
    }
    int node = blockIdx.x * 256 + t;
    int excl = s0 + sh[t] - h;
    cur[t] = excl;
    if (node < N) {
        deg[node] = h;
        rowptr[node] = excl;
        atomicAdd(&bh[(blockIdx.x >> 2) * 256 + min(h, 255)], 1);
    }
    if (node == 0) rowptr[N] = bbase[nbuc];
    __syncthreads();
    for (int i = s0 + t; i < s1; i += 256) {
        unsigned p = epack[i];
        int pos = atomicAdd(&cur[p & 255u], 1);
        ssrc[pos] = (int)(p >> 8);
    }
}

// ------------- degree sort offsets (DESCENDING degree) + scatter ------
// Heavy nodes are placed FIRST so the aggregate's long-running groups start
// early and light nodes backfill (grid-drain balance).
__global__ __launch_bounds__(256) void k_sort_off(int* __restrict__ bh, int nb)
{
    int t = threadIdx.x;
    int run = 0;
    int j = 0;
    for (; j + 8 <= nb; j += 8) {
        int v[8];
        #pragma unroll
        for (int u = 0; u < 8; ++u) v[u] = bh[(j + u) * 256 + t];
        #pragma unroll
        for (int u = 0; u < 8; ++u) { bh[(j + u) * 256 + t] = run; run += v[u]; }
    }
    for (; j < nb; ++j) {
        int v = bh[j * 256 + t];
        bh[j * 256 + t] = run;
        run += v;
    }
    __shared__ int sh[256];
    int tot = run;
    sh[t] = tot;
    __syncthreads();
    for (int off = 1; off < 256; off <<= 1) {
        int u = (t >= off) ? sh[t - off] : 0;
        __syncthreads();
        sh[t] += u;
        __syncthreads();
    }
    int total = sh[255];                    // broadcast (valid after last sync)
    int bucket_base = total - sh[t];        // descending: buckets > t go first
    for (int j2 = 0; j2 < nb; ++j2)
        bh[j2 * 256 + t] += bucket_base;
}

// Writes per-group node info {start, end, node} so k_aggregate's dependent
// load chain starts with a single 16-B broadcast load.
__global__ __launch_bounds__(256) void k_sort_scatter(
    const int* __restrict__ deg, const int* __restrict__ bh,
    const int* __restrict__ rowptr, int4* __restrict__ ninfo, int N)
{
    __shared__ int cur[256];
    int t = threadIdx.x;
    cur[t] = bh[blockIdx.x * 256 + t];
    __syncthreads();
    int base = blockIdx.x * 1024;
    #pragma unroll
    for (int g = 0; g < 4; ++g) {
        int i = base + g * 256 + t;
        if (i < N) {
            int pos = atomicAdd(&cur[min(deg[i], 255)], 1);
            ninfo[pos] = make_int4(rowptr[i], rowptr[i + 1], i, 0);
        }
    }
}

// ---------------- single-pass softmax + weighted aggregation ----------------
// 16 lanes per node (descending-degree order), 4 nodes per wave. 8 edges
// batched per iteration; tail edges index-clamped+predicated. Logits are
// pre-scaled by log2(e) so exp2f (bare v_exp_f32) is exact softmax math.
template<bool OUTBF16>
__global__ __launch_bounds__(256) void k_aggregate(
    const int4* __restrict__ ninfo, const int* __restrict__ ssrc,
    const float* __restrict__ as, const float* __restrict__ ad,
    const unsigned short* __restrict__ hbf, const float* __restrict__ bias,
    void* __restrict__ outv, int N)
{
    int gi = (blockIdx.x * 256 + threadIdx.x) >> 4;
    if (gi >= N) return;
    const int4 ni   = ninfo[gi];           // broadcast within the 16-lane group
    const int start = ni.x, end = ni.y, node = ni.z;
    const int l16   = threadIdx.x & 15;
    const int hb    = l16 >> 2;
    const int c0    = l16 * 8;
    const float adB = ad[node * NHEADS + hb];

    float a0=0.f,a1=0.f,a2=0.f,a3=0.f,a4=0.f,a5=0.f,a6=0.f,a7=0.f;
    float dacc = 0.f;
    for (int base = start; base < end; base += 8) {
        int   sj[8];
        float fj[8];
        uint4 hj[8];
        #pragma unroll
        for (int j = 0; j < 8; ++j)
            sj[j] = ssrc[min(base + j, end - 1)];
        #pragma unroll
        for (int j = 0; j < 8; ++j)
            fj[j] = as[sj[j] * NHEADS + hb];
        #pragma unroll
        for (int j = 0; j < 8; ++j)
            hj[j] = *(const uint4*)(hbf + (size_t)sj[j] * F + c0);
        #pragma unroll
        for (int j = 0; j < 8; ++j) {
            float ex = (base + j < end) ? exp2f(lrelu(fj[j] + adB)) : 0.f;
            dacc += ex;
            a0 = fmaf(ex, __uint_as_float(hj[j].x << 16),         a0);
            a1 = fmaf(ex, __uint_as_float(hj[j].x & 0xffff0000u), a1);
            a2 = fmaf(ex, __uint_as_float(hj[j].y << 16),         a2);
            a3 = fmaf(ex, __uint_as_float(hj[j].y & 0xffff0000u), a3);
            a4 = fmaf(ex, __uint_as_float(hj[j].z << 16),         a4);
            a5 = fmaf(ex, __uint_as_float(hj[j].z & 0xffff0000u), a5);
            a6 = fmaf(ex, __uint_as_float(hj[j].w << 16),         a6);
            a7 = fmaf(ex, __uint_as_float(hj[j].w & 0xffff0000u), a7);
        }
    }
    float inv = 1.f / dacc;
    float v[8] = {a0,a1,a2,a3,a4,a5,a6,a7};
    #pragma unroll
    for (int k = 0; k < 8; ++k) {
        float t = v[k] * inv + bias[c0 + k];
        v[k] = t > 0.f ? t : expm1f(t);
    }
    if (OUTBF16) {
        u32x4 o;
        o.x = (unsigned)cvt_bf16(v[0]) | ((unsigned)cvt_bf16(v[1]) << 16);
        o.y = (unsigned)cvt_bf16(v[2]) | ((unsigned)cvt_bf16(v[3]) << 16);
        o.z = (unsigned)cvt_bf16(v[4]) | ((unsigned)cvt_bf16(v[5]) << 16);
        o.w = (unsigned)cvt_bf16(v[6]) | ((unsigned)cvt_bf16(v[7]) << 16);
        __builtin_nontemporal_store(o,
            (u32x4*)((unsigned short*)outv + (size_t)node * F + c0));
    } else {
        f32x4 o0 = {v[0], v[1], v[2], v[3]};
        f32x4 o1 = {v[4], v[5], v[6], v[7]};
        float* op = (float*)outv + (size_t)node * F + c0;
        __builtin_nontemporal_store(o0, (f32x4*)op);
        __builtin_nontemporal_store(o1, (f32x4*)(op + 4));
    }
}

extern "C" void kernel_launch(void* const* d_in, const int* in_sizes, int n_in,
                              void* d_out, int out_size, void* d_ws, size_t ws_size,
                              hipStream_t stream)
{
    const float* x      = (const float*)d_in[0];
    const int*   eidx   = (const int*)d_in[1];
    const float* W1     = (const float*)d_in[2];
    const float* a_src1 = (const float*)d_in[3];
    const float* a_dst1 = (const float*)d_in[4];
    const float* b1     = (const float*)d_in[5];
    const float* W2     = (const float*)d_in[6];
    const float* a_src2 = (const float*)d_in[7];
    const float* a_dst2 = (const float*)d_in[8];
    const float* b2     = (const float*)d_in[9];

    const int N = in_sizes[0] / F;
    const int E = in_sizes[1] / 2;
    const int TOT = E + N;
    const int* src = eidx;
    const int* dst = eidx + E;

    const int nbuc = (N + 255) / 256;        // coarse buckets (dst>>8)
    const int nab  = (TOT + ACH - 1) / ACH;  // pass-A blocks
    const int nb   = (N + 1023) / 1024;      // degree-sort blocks

    // workspace layout
    unsigned* epack = (unsigned*)d_ws;                     // TOT
    unsigned short* hbf    = (unsigned short*)(epack + TOT);   // N*F bf16
    unsigned short* out1bf = hbf + (size_t)N * F;          // N*F bf16
    float* as = (float*)(out1bf + (size_t)N * F);          // N*4
    float* ad = as + (size_t)N * NHEADS;                   // N*4
    int* deg    = (int*)(ad + (size_t)N * NHEADS);         // N
    int* rowptr = deg + N;                                 // N+1
    int* ssrc   = rowptr + N + 1;                          // TOT
    int4* ninfo = (int4*)(((uintptr_t)(ssrc + TOT) + 15) & ~(uintptr_t)15); // N
    int* bh     = (int*)(ninfo + N);                       // nb*256
    int* bha    = bh + (size_t)nb * 256;                   // nab*nbuc
    int* btot   = bha + (size_t)nab * nbuc;                // nbuc (unused, kept for layout)
    int* bbase  = btot + nbuc;                             // nbuc+1
    short* Wb1  = (short*)(((uintptr_t)(bbase + nbuc + 1) + 15) & ~(uintptr_t)15);

    const int gemmBlocks = (N + 63) / 64;
    const int aggBlocks  = (N + 15) / 16;

    // ---- W pre-pack (both layers, one launch) ----
    k_packW2<<<144, 256, 0, stream>>>(W1, a_src1, a_dst1, W2, a_src2, a_dst2, Wb1);
    short* Wb2 = Wb1 + 36 * 512;

    // ---- CSR build via coarse buckets ----
    k_bhist<<<nab, 512, 0, stream>>>(src, dst, bha, nbuc, E, TOT);
    k_bscan<<<1, 512, 0, stream>>>(bha, bbase, bh, nbuc, nab, nb * 256);
    k_bscatter<<<nab, 512, 0, stream>>>(src, dst, bha, bbase, epack, nbuc, E, TOT);
    k_bfinal<<<nbuc, 256, 0, stream>>>(epack, bbase, deg, rowptr, ssrc, bh, N, nbuc);

    // ---- degree sort (descending) -> ninfo {start, end, node} ----
    k_sort_off<<<1, 256, 0, stream>>>(bh, nb);
    k_sort_scatter<<<nb, 256, 0, stream>>>(deg, bh, rowptr, ninfo, N);

    // ---- layer 1: x (f32) -> out1bf (bf16) ----
    k_gemm_mfma<false><<<gemmBlocks, 256, 0, stream>>>(x, Wb1, hbf, as, ad, N);
    k_aggregate<true><<<aggBlocks, 256, 0, stream>>>(ninfo, ssrc, as, ad, hbf, b1, out1bf, N);

    // ---- layer 2: out1bf (bf16) -> d_out (f32) ----
    k_gemm_mfma<true><<<gemmBlocks, 256, 0, stream>>>(out1bf, Wb2, hbf, as, ad, N);
    k_aggregate<false><<<aggBlocks, 256, 0, stream>>>(ninfo, ssrc, as, ad, hbf, b2, d_out, N);
}